// Round 3
// baseline (248.123 us; speedup 1.0000x reference)
//
#include <hip/hip_runtime.h>
#include <math.h>

typedef __bf16 bf16x8 __attribute__((ext_vector_type(8)));
typedef float  f32x4  __attribute__((ext_vector_type(4)));
typedef unsigned short us4 __attribute__((ext_vector_type(4)));

constexpr int N_EMBD = 1024;
constexpr int T_SEQ  = 128;
constexpr int HS     = 128;
constexpr int BATCH  = 256;

__device__ __forceinline__ void async16(const void* g, void* l) {
    __builtin_amdgcn_global_load_lds(
        (const __attribute__((address_space(1))) unsigned int*)g,
        (__attribute__((address_space(3))) unsigned int*)l, 16, 0, 0);
}
__device__ __forceinline__ unsigned short bfbits(float f) {
    return __builtin_bit_cast(unsigned short, (__bf16)f);
}
__device__ __forceinline__ f32x4 zero4() {
    f32x4 z = {0.f, 0.f, 0.f, 0.f};
    return z;
}

// ---------------- Kernel 0: W cast + transpose ----------------
// Wt[nt*128 + n][k] = W_nt[k][n] as bf16.  48 blocks = 3 nt x 16 k-chunks.
__global__ __launch_bounds__(256) void wcast(
    const float* __restrict__ Wq, const float* __restrict__ Wk,
    const float* __restrict__ Wv, unsigned short* __restrict__ Wt)
{
    __shared__ unsigned short tile[64][130];
    const int bid = blockIdx.x;
    const int nt  = bid >> 4;
    const int k0  = (bid & 15) << 6;
    const float* src = (nt == 0) ? Wq : ((nt == 1) ? Wk : Wv);
    const int tid = threadIdx.x;
#pragma unroll
    for (int j = 0; j < 32; ++j) {
        int idx = tid + j * 256;
        int k = idx >> 7, n = idx & 127;
        tile[k][n] = bfbits(src[(size_t)(k0 + k) * HS + n]);
    }
    __syncthreads();
#pragma unroll
    for (int j = 0; j < 32; ++j) {
        int idx = tid + j * 256;
        int n = idx >> 6, kk = idx & 63;
        Wt[(size_t)(nt * 128 + n) * N_EMBD + k0 + kk] = tile[kk][n];
    }
}

// ---------------- Kernel A: QKV GEMM + RoPE -> workspace ----------------
// 512 blocks x 256 threads (4 waves). Block = 64 x-rows (half a batch) x all
// 384 output cols. LDS 58 KB -> 2 independent blocks/CU (two barrier domains).
//   A dbuf [2][64 rows][80 B]  @ 0     (bf16, +16 B row pad -> 2-way max)
//   B dbuf [2][384 rows][64 B] @ 10240 (bf16, XOR-swizzled 16 B granules)
// Loop: ONE barrier per BK=32 step; prefetch A->regs + B->async16 into buf^1
// before the 24 MFMAs; cvt+ds_write A after (sched_barrier-pinned).
// Epilogue: RoPE on q/k tiles -> qr/kr bf16 [b][t][d]; v -> vT bf16 [b][d][t].
__global__ __launch_bounds__(256, 2) void qkv_rope(
    const float* __restrict__ x,
    const unsigned short* __restrict__ Wt,
    unsigned short* __restrict__ qr,
    unsigned short* __restrict__ kr,
    unsigned short* __restrict__ vT)
{
    __shared__ char lds[59392];
    constexpr int AST = 0,     ASZ = 5120;    // [64][80]
    constexpr int BST = 10240, BSZ = 24576;   // [384][64]

    const int tid  = threadIdx.x;
    const int w    = tid >> 6;
    const int l    = tid & 63;
    const int cl   = l & 15;
    const int quad = l >> 4;
    const int bx   = blockIdx.x;
    const int b    = bx >> 1;
    const int half = bx & 1;
    const int row0 = b * 128 + half * 64;

    // A staging: 4 threads/row, 8 f32 each
    const int ar = tid >> 2;            // 0..63
    const int ac = (tid & 3) << 3;      // f32 col
    const float* aptr = x + (size_t)(row0 + ar) * N_EMBD + ac;
    // B staging: lane l -> row (l>>2), phys granule (l&3); pre-swizzle source
    const int brow = l >> 2;                 // 0..15
    const int bxo  = ((l & 3) ^ (brow & 3)) << 3;

    f32x4 acc[4][6];
#pragma unroll
    for (int a = 0; a < 4; ++a)
#pragma unroll
        for (int c = 0; c < 6; ++c) acc[a][c] = zero4();

    // prologue: stage chunk 0 into buf 0
    {
#pragma unroll
        for (int jj = 0; jj < 6; ++jj) {
            int n = w * 96 + jj * 16 + brow;
            async16(Wt + (size_t)n * N_EMBD + bxo,
                    lds + BST + (w * 96 + jj * 16) * 64);
        }
        f32x4 a0 = *(const f32x4*)(aptr);
        f32x4 a1 = *(const f32x4*)(aptr + 4);
        bf16x8 aw;
        aw[0] = (__bf16)a0[0]; aw[1] = (__bf16)a0[1];
        aw[2] = (__bf16)a0[2]; aw[3] = (__bf16)a0[3];
        aw[4] = (__bf16)a1[0]; aw[5] = (__bf16)a1[1];
        aw[6] = (__bf16)a1[2]; aw[7] = (__bf16)a1[3];
        *(bf16x8*)(lds + AST + ar * 80 + (tid & 3) * 16) = aw;
        __syncthreads();
    }

    int cur = 0;
#pragma unroll 2
    for (int t = 0; t < 32; ++t) {
        const int kc = (t + 1) << 5;
        f32x4 p0, p1;
        if (t < 31) {
            p0 = *(const f32x4*)(aptr + kc);
            p1 = *(const f32x4*)(aptr + kc + 4);
#pragma unroll
            for (int jj = 0; jj < 6; ++jj) {
                int n = w * 96 + jj * 16 + brow;
                async16(Wt + (size_t)n * N_EMBD + kc + bxo,
                        lds + BST + (cur ^ 1) * BSZ + (w * 96 + jj * 16) * 64);
            }
        }
        const char* Ab = lds + AST + cur * ASZ;
        const char* Bb = lds + BST + cur * BSZ;
        bf16x8 af[4], bf[6];
#pragma unroll
        for (int rt = 0; rt < 4; ++rt)
            af[rt] = *(const bf16x8*)(Ab + (rt * 16 + cl) * 80 + quad * 16);
#pragma unroll
        for (int ct = 0; ct < 6; ++ct) {
            int n = w * 96 + ct * 16 + cl;
            bf[ct] = *(const bf16x8*)(Bb + n * 64 + ((quad ^ (n & 3)) << 4));
        }
#pragma unroll
        for (int rt = 0; rt < 4; ++rt)
#pragma unroll
            for (int ct = 0; ct < 6; ++ct)
                acc[rt][ct] = __builtin_amdgcn_mfma_f32_16x16x32_bf16(
                    af[rt], bf[ct], acc[rt][ct], 0, 0, 0);
        if (t < 31) {
            __builtin_amdgcn_sched_barrier(0);
            bf16x8 aw;
            aw[0] = (__bf16)p0[0]; aw[1] = (__bf16)p0[1];
            aw[2] = (__bf16)p0[2]; aw[3] = (__bf16)p0[3];
            aw[4] = (__bf16)p1[0]; aw[5] = (__bf16)p1[1];
            aw[6] = (__bf16)p1[2]; aw[7] = (__bf16)p1[3];
            *(bf16x8*)(lds + AST + (cur ^ 1) * ASZ + ar * 80 + (tid & 3) * 16) = aw;
        }
        __syncthreads();
        cur ^= 1;
    }

    // epilogue: RoPE on q/k, transpose-store v
    const float LNT = 0.07195578430905272f;   // ln(10000)/128
#pragma unroll
    for (int ct = 0; ct < 6; ++ct) {
        int c0  = w * 96 + ct * 16;
        int ntc = c0 >> 7;                    // 0=q 1=k 2=v (tile-uniform)
        int d   = (c0 & 127) + cl;
        if (ntc < 2) {
            unsigned short* dst = ((ntc == 0) ? qr : kr) + (size_t)b * 16384;
            float freq = __expf(-(float)(d & ~1) * LNT);
#pragma unroll
            for (int rt = 0; rt < 4; ++rt) {
#pragma unroll
                for (int i = 0; i < 4; ++i) {
                    int tt = half * 64 + rt * 16 + quad * 4 + i;
                    float v = acc[rt][ct][i];
                    float p = __shfl_xor(v, 1);
                    float sn, cs;
                    __sincosf((float)tt * freq, &sn, &cs);
                    float r = ((d & 1) == 0) ? (v * cs - p * sn) : (p * sn + v * cs);
                    dst[(size_t)tt * HS + d] = bfbits(r);
                }
            }
        } else {
#pragma unroll
            for (int rt = 0; rt < 4; ++rt) {
                int t0 = half * 64 + rt * 16 + quad * 4;
                us4 u;
                u.x = bfbits(acc[rt][ct][0]);
                u.y = bfbits(acc[rt][ct][1]);
                u.z = bfbits(acc[rt][ct][2]);
                u.w = bfbits(acc[rt][ct][3]);
                *(us4*)(vT + (size_t)b * 16384 + (size_t)d * T_SEQ + t0) = u;
            }
        }
    }
}

// ---------------- Kernel B: causal attention, barrier-free waves ----------------
// 512 blocks x 256 threads. Wave = 16 q-rows of one batch; reads q/k/vT straight
// from global (L2/L3-resident, ~25 MB); P in a private 16x272 B LDS slice.
// batch = bx&255, seg = (bx>>8)*4 + w  (pairs light+heavy segments per CU).
__global__ __launch_bounds__(256, 2) void attn(
    const unsigned short* __restrict__ qr,
    const unsigned short* __restrict__ kr,
    const unsigned short* __restrict__ vT,
    float* __restrict__ out)
{
    __shared__ char lds[17408];
    const int tid  = threadIdx.x;
    const int w    = tid >> 6;
    const int l    = tid & 63;
    const int cl   = l & 15;
    const int quad = l >> 4;
    const int bx   = blockIdx.x;
    const int b    = bx & 255;
    const int seg  = ((bx >> 8) << 2) + w;   // 0..7
    const int nct  = seg + 1;
    const int nks  = (seg + 2) >> 1;
    char* pl = lds + w * 4352;               // 16 rows x 272 B private

    const unsigned short* qb = qr + (size_t)b * 16384;
    const unsigned short* kb = kr + (size_t)b * 16384;
    const unsigned short* vb = vT + (size_t)b * 16384;

    bf16x8 qf[4];
#pragma unroll
    for (int ks = 0; ks < 4; ++ks)
        qf[ks] = *(const bf16x8*)(qb + (seg * 16 + cl) * HS + ks * 32 + quad * 8);

    f32x4 s[8];
#pragma unroll
    for (int ct = 0; ct < 8; ++ct) s[ct] = zero4();

#pragma unroll
    for (int ct = 0; ct < 8; ++ct) if (ct < nct) {
#pragma unroll
        for (int ks = 0; ks < 4; ++ks) {
            bf16x8 kk = *(const bf16x8*)(kb + (ct * 16 + cl) * HS + ks * 32 + quad * 8);
            s[ct] = __builtin_amdgcn_mfma_f32_16x16x32_bf16(qf[ks], kk, s[ct], 0, 0, 0);
        }
    }

    const float scale = 0.08838834764831845f;   // 1/sqrt(128)
#pragma unroll
    for (int i = 0; i < 4; ++i) {
        int t = seg * 16 + quad * 4 + i;
        float mx = -3.0e38f;
#pragma unroll
        for (int ct = 0; ct < 8; ++ct) if (ct < nct) {
            int col = ct * 16 + cl;
            float v = s[ct][i] * scale;
            v = (col <= t) ? v : -INFINITY;
            s[ct][i] = v;
            mx = fmaxf(mx, v);
        }
        mx = fmaxf(mx, __shfl_xor(mx, 1));
        mx = fmaxf(mx, __shfl_xor(mx, 2));
        mx = fmaxf(mx, __shfl_xor(mx, 4));
        mx = fmaxf(mx, __shfl_xor(mx, 8));
        float sum = 0.f;
#pragma unroll
        for (int ct = 0; ct < 8; ++ct) if (ct < nct) {
            float p = __expf(s[ct][i] - mx);
            s[ct][i] = p;
            sum += p;
        }
        sum += __shfl_xor(sum, 1);
        sum += __shfl_xor(sum, 2);
        sum += __shfl_xor(sum, 4);
        sum += __shfl_xor(sum, 8);
        float inv = 1.0f / sum;
        int rl = quad * 4 + i;
#pragma unroll
        for (int ct = 0; ct < 8; ++ct) if (ct < nct) {
            *(unsigned short*)(pl + rl * 272 + (ct * 16 + cl) * 2) =
                bfbits(s[ct][i] * inv);
        }
        if ((seg & 1) == 0) {   // PV consumes one 16-col tile past stored range
            *(unsigned short*)(pl + rl * 272 + (nct * 16 + cl) * 2) = 0;
        }
    }
    // same-wave ds_write -> ds_read: compiler inserts lgkmcnt wait; no barrier.

    bf16x8 ap[4];
#pragma unroll
    for (int ks = 0; ks < 4; ++ks) if (ks < nks)
        ap[ks] = *(const bf16x8*)(pl + cl * 272 + (ks * 4 + quad) * 16);

    f32x4 o[8];
#pragma unroll
    for (int ct = 0; ct < 8; ++ct) o[ct] = zero4();

#pragma unroll
    for (int ct = 0; ct < 8; ++ct) {
#pragma unroll
        for (int ks = 0; ks < 4; ++ks) if (ks < nks) {
            bf16x8 vv = *(const bf16x8*)(vb + (ct * 16 + cl) * T_SEQ + ks * 32 + quad * 8);
            o[ct] = __builtin_amdgcn_mfma_f32_16x16x32_bf16(ap[ks], vv, o[ct], 0, 0, 0);
        }
    }

#pragma unroll
    for (int ct = 0; ct < 8; ++ct)
#pragma unroll
        for (int i = 0; i < 4; ++i) {
            int t = seg * 16 + quad * 4 + i;
            out[(size_t)b * 16384 + (size_t)t * HS + ct * 16 + cl] = o[ct][i];
        }
}

// ---------------- launch ----------------
extern "C" void kernel_launch(void* const* d_in, const int* in_sizes, int n_in,
                              void* d_out, int out_size, void* d_ws, size_t ws_size,
                              hipStream_t stream) {
    const float* x  = (const float*)d_in[0];
    const float* Wq = (const float*)d_in[1];
    const float* Wk = (const float*)d_in[2];
    const float* Wv = (const float*)d_in[3];
    float* out = (float*)d_out;

    char* ws = (char*)d_ws;
    unsigned short* Wt = (unsigned short*)ws;                    // 768 KB
    unsigned short* q  = (unsigned short*)(ws + (1  << 20));     // 8 MB
    unsigned short* k  = (unsigned short*)(ws + (9  << 20));     // 8 MB
    unsigned short* vT = (unsigned short*)(ws + (17 << 20));     // 8 MB

    wcast<<<48, 256, 0, stream>>>(Wq, Wk, Wv, Wt);
    qkv_rope<<<512, 256, 0, stream>>>(x, Wt, q, k, vT);
    attn<<<512, 256, 0, stream>>>(q, k, vT, out);
}

// Round 5
// 244.366 us; speedup vs baseline: 1.0154x; 1.0154x over previous
//
#include <hip/hip_runtime.h>
#include <math.h>

typedef __bf16 bf16x8 __attribute__((ext_vector_type(8)));
typedef float  f32x4  __attribute__((ext_vector_type(4)));
typedef unsigned short us4 __attribute__((ext_vector_type(4)));

constexpr int N_EMBD = 1024;
constexpr int T_SEQ  = 128;
constexpr int HS     = 128;
constexpr int BATCH  = 256;

__device__ __forceinline__ void async16(const void* g, void* l) {
    __builtin_amdgcn_global_load_lds(
        (const __attribute__((address_space(1))) unsigned int*)g,
        (__attribute__((address_space(3))) unsigned int*)l, 16, 0, 0);
}
__device__ __forceinline__ unsigned short bfbits(float f) {
    return __builtin_bit_cast(unsigned short, (__bf16)f);
}
__device__ __forceinline__ f32x4 zero4() {
    f32x4 z = {0.f, 0.f, 0.f, 0.f};
    return z;
}

// ---------------- Kernel 0: W cast + transpose ----------------
// Wt[nt*128 + n][k] = W_nt[k][n] as bf16.  48 blocks = 3 nt x 16 k-chunks.
__global__ __launch_bounds__(256) void wcast(
    const float* __restrict__ Wq, const float* __restrict__ Wk,
    const float* __restrict__ Wv, unsigned short* __restrict__ Wt)
{
    __shared__ unsigned short tile[64][130];
    const int bid = blockIdx.x;
    const int nt  = bid >> 4;
    const int k0  = (bid & 15) << 6;
    const float* src = (nt == 0) ? Wq : ((nt == 1) ? Wk : Wv);
    const int tid = threadIdx.x;
#pragma unroll
    for (int j = 0; j < 32; ++j) {
        int idx = tid + j * 256;
        int k = idx >> 7, n = idx & 127;
        tile[k][n] = bfbits(src[(size_t)(k0 + k) * HS + n]);
    }
    __syncthreads();
#pragma unroll
    for (int j = 0; j < 32; ++j) {
        int idx = tid + j * 256;
        int n = idx >> 6, kk = idx & 63;
        Wt[(size_t)(nt * 128 + n) * N_EMBD + k0 + kk] = tile[kk][n];
    }
}

// ---------------- Kernel A: QKV GEMM + RoPE, counted-vmcnt pipeline ----------
// 512 blocks x 256 threads (4 waves), 2 blocks/CU (64 KB LDS).
// Block = 64 x-rows x 384 cols, BK=32, 32 chunks, double-buffered:
//   A buf [2][64 rows][32 f32 = 128 B] @ 0     (granule-XOR swizzle g^=row&7)
//   B buf [2][384 rows][64 B bf16]     @ 16384 (granule-XOR swizzle g^=row&3)
// All staging via global_load_lds: 8 async16/wave/step (2 A + 6 B).
// T4 discipline: raw s_barrier + asm s_waitcnt vmcnt(8) — next chunk's 8
// asyncs stay in flight across the barrier (never drain to 0 mid-loop).
// Step t: [stage t+1 -> buf^1 | vmcnt(8); bar | ds_read+cvt+24 MFMA | lgkm(0); bar]
__global__ __launch_bounds__(256, 2) void qkv_rope(
    const float* __restrict__ x,
    const unsigned short* __restrict__ Wt,
    unsigned short* __restrict__ qr,
    unsigned short* __restrict__ kr,
    unsigned short* __restrict__ vT)
{
    __shared__ char lds[65536];
    constexpr int ASZ  = 8192;
    constexpr int BOFF = 16384, BSZ = 24576;

    const int tid  = threadIdx.x;
    const int w    = tid >> 6;
    const int l    = tid & 63;
    const int cl   = l & 15;
    const int quad = l >> 4;
    const int bx   = blockIdx.x;
    const int b    = bx >> 1;
    const int half = bx & 1;
    const int row0 = b * 128 + half * 64;

    // A staging: wave w stages chunk rows [16w,16w+16) via 2 async16.
    // async j, lane l: row 16w+8j+(l>>3), source granule (l&7)^(l>>3).
    const int arj = l >> 3;
    const int agr = (l & 7) ^ arj;
    const float* aS0 = x + (size_t)(row0 + 16 * w + arj) * N_EMBD + agr * 4;
    const float* aS1 = x + (size_t)(row0 + 16 * w + 8 + arj) * N_EMBD + agr * 4;

    // B staging: wave w stages rows [96w,96w+96) via 6 async16.
    // async jj, lane l: row 96w+16jj+(l>>2), source granule (l&3)^(row&3).
    const int brow = l >> 2;
    const int bxo  = ((l & 3) ^ (brow & 3)) << 3;
    const unsigned short* bS0 = Wt + (size_t)(w * 96 +  0 + brow) * N_EMBD + bxo;
    const unsigned short* bS1 = Wt + (size_t)(w * 96 + 16 + brow) * N_EMBD + bxo;
    const unsigned short* bS2 = Wt + (size_t)(w * 96 + 32 + brow) * N_EMBD + bxo;
    const unsigned short* bS3 = Wt + (size_t)(w * 96 + 48 + brow) * N_EMBD + bxo;
    const unsigned short* bS4 = Wt + (size_t)(w * 96 + 64 + brow) * N_EMBD + bxo;
    const unsigned short* bS5 = Wt + (size_t)(w * 96 + 80 + brow) * N_EMBD + bxo;

    f32x4 acc[4][6];
#pragma unroll
    for (int a = 0; a < 4; ++a)
#pragma unroll
        for (int c = 0; c < 6; ++c) acc[a][c] = zero4();

#define STAGE(DST)                                                            \
    __builtin_amdgcn_sched_barrier(0);                                        \
    async16(aS0, lds + (DST) * ASZ + (2 * w + 0) * 1024);                     \
    async16(aS1, lds + (DST) * ASZ + (2 * w + 1) * 1024);                     \
    async16(bS0, lds + BOFF + (DST) * BSZ + (w * 96 +  0) * 64);              \
    async16(bS1, lds + BOFF + (DST) * BSZ + (w * 96 + 16) * 64);              \
    async16(bS2, lds + BOFF + (DST) * BSZ + (w * 96 + 32) * 64);              \
    async16(bS3, lds + BOFF + (DST) * BSZ + (w * 96 + 48) * 64);              \
    async16(bS4, lds + BOFF + (DST) * BSZ + (w * 96 + 64) * 64);              \
    async16(bS5, lds + BOFF + (DST) * BSZ + (w * 96 + 80) * 64);              \
    aS0 += 32; aS1 += 32;                                                     \
    bS0 += 32; bS1 += 32; bS2 += 32; bS3 += 32; bS4 += 32; bS5 += 32;         \
    __builtin_amdgcn_sched_barrier(0);

#define COMPUTE(CSEL) {                                                       \
    const char* Ab = lds + (CSEL) * ASZ;                                      \
    const char* Bb = lds + BOFF + (CSEL) * BSZ;                               \
    bf16x8 af[4]; bf16x8 bf[6];                                               \
    _Pragma("unroll")                                                         \
    for (int rt = 0; rt < 4; ++rt) {                                          \
        int m = rt * 16 + cl;                                                 \
        f32x4 u0 = *(const f32x4*)(Ab + m * 128 + (((quad * 2)     ^ (m & 7)) << 4)); \
        f32x4 u1 = *(const f32x4*)(Ab + m * 128 + (((quad * 2 + 1) ^ (m & 7)) << 4)); \
        af[rt][0] = (__bf16)u0[0]; af[rt][1] = (__bf16)u0[1];                 \
        af[rt][2] = (__bf16)u0[2]; af[rt][3] = (__bf16)u0[3];                 \
        af[rt][4] = (__bf16)u1[0]; af[rt][5] = (__bf16)u1[1];                 \
        af[rt][6] = (__bf16)u1[2]; af[rt][7] = (__bf16)u1[3];                 \
    }                                                                         \
    _Pragma("unroll")                                                         \
    for (int ct = 0; ct < 6; ++ct) {                                          \
        int n = w * 96 + ct * 16 + cl;                                        \
        bf[ct] = *(const bf16x8*)(Bb + n * 64 + ((quad ^ (n & 3)) << 4));     \
    }                                                                         \
    _Pragma("unroll")                                                         \
    for (int rt = 0; rt < 4; ++rt)                                            \
        _Pragma("unroll")                                                     \
        for (int ct = 0; ct < 6; ++ct)                                        \
            acc[rt][ct] = __builtin_amdgcn_mfma_f32_16x16x32_bf16(            \
                af[rt], bf[ct], acc[rt][ct], 0, 0, 0);                        \
}

#define GSTEP(CSEL)                                                           \
    STAGE((CSEL) ^ 1)                                                         \
    asm volatile("s_waitcnt vmcnt(8)" ::: "memory");                          \
    __builtin_amdgcn_sched_barrier(0);                                        \
    __builtin_amdgcn_s_barrier();                                             \
    __builtin_amdgcn_sched_barrier(0);                                        \
    COMPUTE(CSEL)                                                             \
    __builtin_amdgcn_sched_barrier(0);                                        \
    asm volatile("s_waitcnt lgkmcnt(0)" ::: "memory");                        \
    __builtin_amdgcn_s_barrier();

    // prologue: stage chunk 0 into buf 0 (stays in flight; drained at step 0)
    STAGE(0)

    // main loop: steps 0..30 (each stages chunk t+1), uniform vmcnt(8)
    for (int t = 0; t < 30; t += 2) {
        GSTEP(0)
        GSTEP(1)
    }
    GSTEP(0)   // t = 30

    // t = 31: final chunk, nothing left to stage
    __builtin_amdgcn_sched_barrier(0);
    asm volatile("s_waitcnt vmcnt(0)" ::: "memory");
    __builtin_amdgcn_sched_barrier(0);
    __builtin_amdgcn_s_barrier();
    __builtin_amdgcn_sched_barrier(0);
    COMPUTE(1)

#undef STAGE
#undef COMPUTE
#undef GSTEP

    // epilogue: RoPE on q/k, transpose-store v (global writes only; no barrier)
    const float LNT = 0.07195578430905272f;   // ln(10000)/128
#pragma unroll
    for (int ct = 0; ct < 6; ++ct) {
        int c0  = w * 96 + ct * 16;
        int ntc = c0 >> 7;                    // 0=q 1=k 2=v (tile-uniform)
        int d   = (c0 & 127) + cl;
        if (ntc < 2) {
            unsigned short* dst = ((ntc == 0) ? qr : kr) + (size_t)b * 16384;
            float freq = __expf(-(float)(d & ~1) * LNT);
#pragma unroll
            for (int rt = 0; rt < 4; ++rt) {
#pragma unroll
                for (int i = 0; i < 4; ++i) {
                    int tt = half * 64 + rt * 16 + quad * 4 + i;
                    float v = acc[rt][ct][i];
                    float p = __shfl_xor(v, 1);
                    float sn, cs;
                    __sincosf((float)tt * freq, &sn, &cs);
                    float r = ((d & 1) == 0) ? (v * cs - p * sn) : (p * sn + v * cs);
                    dst[(size_t)tt * HS + d] = bfbits(r);
                }
            }
        } else {
#pragma unroll
            for (int rt = 0; rt < 4; ++rt) {
                int t0 = half * 64 + rt * 16 + quad * 4;
                us4 u;
                u.x = bfbits(acc[rt][ct][0]);
                u.y = bfbits(acc[rt][ct][1]);
                u.z = bfbits(acc[rt][ct][2]);
                u.w = bfbits(acc[rt][ct][3]);
                *(us4*)(vT + (size_t)b * 16384 + (size_t)d * T_SEQ + t0) = u;
            }
        }
    }
}

// ---------------- Kernel B: causal attention, barrier-free waves ----------------
// 512 blocks x 256 threads. Wave = 16 q-rows of one batch; reads q/k/vT straight
// from global (L2/L3-resident, ~25 MB); P in a private 16x272 B LDS slice.
// batch = bx&255, seg = (bx>>8)*4 + w  (pairs light+heavy segments per CU).
__global__ __launch_bounds__(256, 2) void attn(
    const unsigned short* __restrict__ qr,
    const unsigned short* __restrict__ kr,
    const unsigned short* __restrict__ vT,
    float* __restrict__ out)
{
    __shared__ char lds[17408];
    const int tid  = threadIdx.x;
    const int w    = tid >> 6;
    const int l    = tid & 63;
    const int cl   = l & 15;
    const int quad = l >> 4;
    const int bx   = blockIdx.x;
    const int b    = bx & 255;
    const int seg  = ((bx >> 8) << 2) + w;   // 0..7
    const int nct  = seg + 1;
    const int nks  = (seg + 2) >> 1;
    char* pl = lds + w * 4352;               // 16 rows x 272 B private

    const unsigned short* qb = qr + (size_t)b * 16384;
    const unsigned short* kb = kr + (size_t)b * 16384;
    const unsigned short* vb = vT + (size_t)b * 16384;

    bf16x8 qf[4];
#pragma unroll
    for (int ks = 0; ks < 4; ++ks)
        qf[ks] = *(const bf16x8*)(qb + (seg * 16 + cl) * HS + ks * 32 + quad * 8);

    f32x4 s[8];
#pragma unroll
    for (int ct = 0; ct < 8; ++ct) s[ct] = zero4();

#pragma unroll
    for (int ct = 0; ct < 8; ++ct) if (ct < nct) {
#pragma unroll
        for (int ks = 0; ks < 4; ++ks) {
            bf16x8 kk = *(const bf16x8*)(kb + (ct * 16 + cl) * HS + ks * 32 + quad * 8);
            s[ct] = __builtin_amdgcn_mfma_f32_16x16x32_bf16(qf[ks], kk, s[ct], 0, 0, 0);
        }
    }

    const float scale = 0.08838834764831845f;   // 1/sqrt(128)
#pragma unroll
    for (int i = 0; i < 4; ++i) {
        int t = seg * 16 + quad * 4 + i;
        float mx = -3.0e38f;
#pragma unroll
        for (int ct = 0; ct < 8; ++ct) if (ct < nct) {
            int col = ct * 16 + cl;
            float v = s[ct][i] * scale;
            v = (col <= t) ? v : -INFINITY;
            s[ct][i] = v;
            mx = fmaxf(mx, v);
        }
        mx = fmaxf(mx, __shfl_xor(mx, 1));
        mx = fmaxf(mx, __shfl_xor(mx, 2));
        mx = fmaxf(mx, __shfl_xor(mx, 4));
        mx = fmaxf(mx, __shfl_xor(mx, 8));
        float sum = 0.f;
#pragma unroll
        for (int ct = 0; ct < 8; ++ct) if (ct < nct) {
            float p = __expf(s[ct][i] - mx);
            s[ct][i] = p;
            sum += p;
        }
        sum += __shfl_xor(sum, 1);
        sum += __shfl_xor(sum, 2);
        sum += __shfl_xor(sum, 4);
        sum += __shfl_xor(sum, 8);
        float inv = 1.0f / sum;
        int rl = quad * 4 + i;
#pragma unroll
        for (int ct = 0; ct < 8; ++ct) if (ct < nct) {
            *(unsigned short*)(pl + rl * 272 + (ct * 16 + cl) * 2) =
                bfbits(s[ct][i] * inv);
        }
        if ((seg & 1) == 0) {   // PV consumes one 16-col tile past stored range
            *(unsigned short*)(pl + rl * 272 + (nct * 16 + cl) * 2) = 0;
        }
    }
    // same-wave ds_write -> ds_read: compiler inserts lgkmcnt wait; no barrier.

    bf16x8 ap[4];
#pragma unroll
    for (int ks = 0; ks < 4; ++ks) if (ks < nks)
        ap[ks] = *(const bf16x8*)(pl + cl * 272 + (ks * 4 + quad) * 16);

    f32x4 o[8];
#pragma unroll
    for (int ct = 0; ct < 8; ++ct) o[ct] = zero4();

#pragma unroll
    for (int ct = 0; ct < 8; ++ct) {
#pragma unroll
        for (int ks = 0; ks < 4; ++ks) if (ks < nks) {
            bf16x8 vv = *(const bf16x8*)(vb + (ct * 16 + cl) * T_SEQ + ks * 32 + quad * 8);
            o[ct] = __builtin_amdgcn_mfma_f32_16x16x32_bf16(ap[ks], vv, o[ct], 0, 0, 0);
        }
    }

#pragma unroll
    for (int ct = 0; ct < 8; ++ct)
#pragma unroll
        for (int i = 0; i < 4; ++i) {
            int t = seg * 16 + quad * 4 + i;
            out[(size_t)b * 16384 + (size_t)t * HS + ct * 16 + cl] = o[ct][i];
        }
}

// ---------------- launch ----------------
extern "C" void kernel_launch(void* const* d_in, const int* in_sizes, int n_in,
                              void* d_out, int out_size, void* d_ws, size_t ws_size,
                              hipStream_t stream) {
    const float* x  = (const float*)d_in[0];
    const float* Wq = (const float*)d_in[1];
    const float* Wk = (const float*)d_in[2];
    const float* Wv = (const float*)d_in[3];
    float* out = (float*)d_out;

    char* ws = (char*)d_ws;
    unsigned short* Wt = (unsigned short*)ws;                    // 768 KB
    unsigned short* q  = (unsigned short*)(ws + (1  << 20));     // 8 MB
    unsigned short* k  = (unsigned short*)(ws + (9  << 20));     // 8 MB
    unsigned short* vT = (unsigned short*)(ws + (17 << 20));     // 8 MB

    wcast<<<48, 256, 0, stream>>>(Wq, Wk, Wv, Wt);
    qkv_rope<<<512, 256, 0, stream>>>(x, Wt, q, k, vT);
    attn<<<512, 256, 0, stream>>>(q, k, vT, out);
}